// Round 6
// baseline (3839.290 us; speedup 1.0000x reference)
//
#include <hip/hip_runtime.h>

// K-means, B=16, N=96*96=9216, C=256, K=21, 20 iterations.
//
// R7: PERF — split update into compact/gather/csq for parallelism.
// NUMERICS FROZEN from R5/R6 (PASS at absmax 4.882812e-04, deterministic).
//
// Correctness ledger: harness np reference is fp32; matching requires
// numpy-correlated fp32 rounding (R4 proved exact arithmetic lands the
// wrong basin). DO NOT change any float op, order, or precision:
//  - dots: ascending-c, 4 interleaved accs, separate mul/add roundings
//  - x_sq/csq: two 128-halves, 8 interleaved accs, pairwise combine
//  - d = (x_sq - 2*dot) + csq, first-min argmin
//  - centroid sums: GLOBAL ascending-n sequential fp32 chain per (k,c)
//  - new_cent = cnt>0 ? sums/max(cnt,1) : old, fp32 state
//
// Perf evidence (R6 rocprof): update_np 206us/iter, VALUBusy 2.6%, occupancy
// 2.3% -> latency-bound: 336 blocks = 1.3/CU, only 8 loads in flight/wave.
// R7: compact_np writes ascending lists to global once per (b,k); then
// update_gather runs 1344 one-wave blocks (4 channel-groups per (b,k)) with
// 16 gathers in flight; csq_np recomputes ||c||^2. Same __fadd_rn chain:
// batch width never reorders adds; tail adds are uniform-guarded ascending.
// No float atomics; output bit-identical every call (graph-safe).

#define BB 16
#define NN 9216
#define CC 256
#define KK 21
#define ITERS 20
#define QTR 2304     // NN/4: points per wave-quarter in compaction

// product with its own fp32 rounding, un-fusable into the consumer add
__device__ __forceinline__ float mul_sep(float a, float b) {
  float t = a * b;
  asm("" : "+v"(t));   // opaque pass-through: blocks FMA contraction
  return t;
}

// numpy pairwise_sum of v[i]*v[i], i in [0,128): 8 interleaved accumulators,
// combined ((r0+r1)+(r2+r3))+((r4+r5)+(r6+r7)). (n=256 splits into 2 halves.)
__device__ float np_half_sq(const float* v) {
  float r[8];
  #pragma unroll
  for (int j = 0; j < 8; ++j) r[j] = mul_sep(v[j], v[j]);
  for (int i = 8; i < 128; i += 8) {
    #pragma unroll
    for (int j = 0; j < 8; ++j) r[j] = __fadd_rn(r[j], mul_sep(v[i + j], v[i + j]));
  }
  return __fadd_rn(__fadd_rn(__fadd_rn(r[0], r[1]), __fadd_rn(r[2], r[3])),
                   __fadd_rn(__fadd_rn(r[4], r[5]), __fadd_rn(r[6], r[7])));
}

// ---------------------------------------------------------------- decode_idx
__global__ __launch_bounds__(512) void decode_idx(
    const void* __restrict__ raw, int* __restrict__ out) {
  __shared__ int all_ok;
  if (threadIdx.x == 0) all_ok = 1;
  __syncthreads();
  const long long* p64 = (const long long*)raw;
  const int* p32 = (const int*)raw;
  int t = threadIdx.x;
  long long v64 = 0;
  if (t < BB * KK) {
    v64 = p64[t];
    if (v64 < 0 || v64 >= NN) atomicAnd(&all_ok, 0);
  }
  __syncthreads();
  if (t < BB * KK) out[t] = all_ok ? (int)v64 : p32[t];
}

// ---------------------------------------------------------------- gather_init
// One block per (b,k): gather initial centroid; csq via numpy pairwise.
__global__ __launch_bounds__(256) void gather_init(
    const float* __restrict__ x, const int* __restrict__ idx_dec,
    float* __restrict__ cent, float* __restrict__ csq) {
  __shared__ float row[CC];
  int bk = blockIdx.x;
  int b = bk / KK;
  int c = threadIdx.x;
  int idx = idx_dec[bk];
  float v = x[((size_t)b * NN + idx) * CC + c];
  cent[(size_t)bk * CC + c] = v;
  row[c] = v;
  __syncthreads();
  if (threadIdx.x == 0)
    csq[bk] = __fadd_rn(np_half_sq(row), np_half_sq(row + 128));
}

// ---------------------------------------------------------------- assign_np
// (unchanged — numerics frozen)
__global__ __launch_bounds__(256) void assign_np(
    const float* __restrict__ x, const float* __restrict__ cent,
    const float* __restrict__ csq, int* __restrict__ assign) {
  const int nb = NN / 256;      // 36 blocks per batch
  int b = blockIdx.x / nb;
  int n = (blockIdx.x % nb) * 256 + threadIdx.x;
  const float* xp = x + ((size_t)b * NN + n) * CC;
  const float* cp = cent + (size_t)b * KK * CC;
  const float* cq = csq + b * KK;

  float q[KK][4];
  #pragma unroll
  for (int k = 0; k < KK; ++k)
    #pragma unroll
    for (int j = 0; j < 4; ++j) q[k][j] = 0.f;
  float rA[8], rB[8];
  #pragma unroll
  for (int j = 0; j < 8; ++j) { rA[j] = 0.f; rB[j] = 0.f; }

#define CHUNK16(C0, R)                                                        \
  do {                                                                        \
    float xv[16];                                                             \
    {                                                                         \
      float4 t0 = *(const float4*)(xp + (C0));                                \
      float4 t1 = *(const float4*)(xp + (C0) + 4);                            \
      float4 t2 = *(const float4*)(xp + (C0) + 8);                            \
      float4 t3 = *(const float4*)(xp + (C0) + 12);                           \
      xv[0] = t0.x; xv[1] = t0.y; xv[2] = t0.z; xv[3] = t0.w;                 \
      xv[4] = t1.x; xv[5] = t1.y; xv[6] = t1.z; xv[7] = t1.w;                 \
      xv[8] = t2.x; xv[9] = t2.y; xv[10] = t2.z; xv[11] = t2.w;               \
      xv[12] = t3.x; xv[13] = t3.y; xv[14] = t3.z; xv[15] = t3.w;             \
    }                                                                         \
    _Pragma("unroll")                                                         \
    for (int g = 0; g < 16; g += 8) {                                         \
      _Pragma("unroll")                                                       \
      for (int j = 0; j < 8; ++j)                                             \
        R[j] = __fadd_rn(R[j], mul_sep(xv[g + j], xv[g + j]));                \
    }                                                                         \
    _Pragma("unroll")                                                         \
    for (int k = 0; k < KK; ++k) {                                            \
      const float* cpk = cp + k * CC + (C0);  /* wave-uniform address */      \
      _Pragma("unroll")                                                       \
      for (int g2 = 0; g2 < 16; g2 += 4) {                                    \
        _Pragma("unroll")                                                     \
        for (int j = 0; j < 4; ++j)                                           \
          q[k][j] = __fadd_rn(q[k][j], mul_sep(xv[g2 + j], cpk[g2 + j]));     \
      }                                                                       \
    }                                                                         \
  } while (0)

  for (int c0 = 0; c0 < 128; c0 += 16) CHUNK16(c0, rA);
  for (int c0 = 128; c0 < 256; c0 += 16) CHUNK16(c0, rB);
#undef CHUNK16

  float hA = __fadd_rn(__fadd_rn(__fadd_rn(rA[0], rA[1]), __fadd_rn(rA[2], rA[3])),
                       __fadd_rn(__fadd_rn(rA[4], rA[5]), __fadd_rn(rA[6], rA[7])));
  float hB = __fadd_rn(__fadd_rn(__fadd_rn(rB[0], rB[1]), __fadd_rn(rB[2], rB[3])),
                       __fadd_rn(__fadd_rn(rB[4], rB[5]), __fadd_rn(rB[6], rB[7])));
  float xsq = __fadd_rn(hA, hB);

  float best = INFINITY;
  int bestk = 0;
  #pragma unroll
  for (int k = 0; k < KK; ++k) {
    float dk = __fadd_rn(__fadd_rn(q[k][0], q[k][2]), __fadd_rn(q[k][1], q[k][3]));
    float d = __fadd_rn(__fsub_rn(xsq, __fmul_rn(2.0f, dk)), cq[k]);
    if (d < best) { best = d; bestk = k; }   // first-min == np.argmin
  }
  assign[(size_t)b * NN + n] = bestk;
}

// ---------------------------------------------------------------- compact_np
// One block per (b,k): R6's exact ballot compaction (wave quarters, ascending
// n), concatenated to global in wave order -> globally ascending list.
__global__ __launch_bounds__(256) void compact_np(
    const int* __restrict__ assign, int* __restrict__ lists,
    int* __restrict__ counts) {
  __shared__ int idx_lds[4][QTR];   // 36864 B
  __shared__ int wcnt[4];
  int bk = blockIdx.x;
  int b = bk / KK, k = bk % KK;
  int lane = threadIdx.x & 63, w = threadIdx.x >> 6;

  const int* ap = assign + (size_t)b * NN + w * QTR;
  int cnt = 0;
  for (int i = 0; i < QTR; i += 64) {
    int a = ap[i + lane];
    unsigned long long m = __ballot(a == k);
    if (a == k) {
      int pos = cnt + (int)__popcll(m & ((1ull << lane) - 1ull));
      idx_lds[w][pos] = w * QTR + i + lane;
    }
    cnt += (int)__popcll(m);
  }
  if (lane == 0) wcnt[w] = cnt;
  __syncthreads();

  int base = 0;
  #pragma unroll
  for (int ww = 0; ww < 4; ++ww) if (ww < w) base += wcnt[ww];
  int* gl = lists + (size_t)bk * NN;
  for (int i = lane; i < cnt; i += 64) gl[base + i] = idx_lds[w][i];
  if (threadIdx.x == 0)
    counts[bk] = wcnt[0] + wcnt[1] + wcnt[2] + wcnt[3];
}

// ---------------------------------------------------------------- update_gather
// 1344 blocks of 64 threads: block = (b,k) x 64-channel group. Gathers the
// precomputed ascending list with 16 loads in flight; the per-(k,c) add chain
// is the SAME strictly-sequential __fadd_rn sequence (batching never reorders
// adds; tail adds uniform-guarded, ascending j). Then cnt>0 ? s/max(cnt,1):old.
__global__ __launch_bounds__(64) void update_gather(
    const float* __restrict__ x, const int* __restrict__ lists,
    const int* __restrict__ counts, float* __restrict__ cent) {
  int blk = blockIdx.x;
  int bk = blk >> 2, g = blk & 3;
  int b = bk / KK;
  int c = g * 64 + threadIdx.x;
  int total = counts[bk];                       // block-uniform
  const int* lst = lists + (size_t)bk * NN;
  const float* xb = x + (size_t)b * NN * CC + c;

  float s = 0.f;
  if (total > 0) {
    int i = 0;
    for (; i + 16 <= total; i += 16) {
      int nn[16];
      float v[16];
      #pragma unroll
      for (int j = 0; j < 16; ++j) nn[j] = lst[i + j];
      #pragma unroll
      for (int j = 0; j < 16; ++j) v[j] = xb[(size_t)nn[j] * CC];
      #pragma unroll
      for (int j = 0; j < 16; ++j) s = __fadd_rn(s, v[j]);  // chain in order
    }
    if (i < total) {
      int rem = total - i;                      // 1..15, block-uniform
      int nn[16];
      float v[16];
      #pragma unroll
      for (int j = 0; j < 16; ++j) nn[j] = lst[(j < rem) ? (i + j) : i];
      #pragma unroll
      for (int j = 0; j < 16; ++j) v[j] = xb[(size_t)nn[j] * CC];
      #pragma unroll
      for (int j = 0; j < 16; ++j)
        if (j < rem) s = __fadd_rn(s, v[j]);    // uniform guard, ascending
    }
  }

  float old = cent[(size_t)bk * CC + c];
  float dv = s / fmaxf((float)total, 1.0f);     // fp32 IEEE division (as R5)
  float nc = (total > 0) ? dv : old;
  cent[(size_t)bk * CC + c] = nc;
}

// ---------------------------------------------------------------- csq_np
// One block per (b,k): numpy-pairwise ||c||^2 of the updated centroid row.
// Identical np_half_sq on identical values as R6's in-kernel row[] path.
__global__ __launch_bounds__(256) void csq_np(
    const float* __restrict__ cent, float* __restrict__ csq) {
  __shared__ float row[CC];
  int bk = blockIdx.x;
  row[threadIdx.x] = cent[(size_t)bk * CC + threadIdx.x];
  __syncthreads();
  if (threadIdx.x == 0)
    csq[bk] = __fadd_rn(np_half_sq(row), np_half_sq(row + 128));
}

// ---------------------------------------------------------------- launch
extern "C" void kernel_launch(void* const* d_in, const int* in_sizes, int n_in,
                              void* d_out, int out_size, void* d_ws, size_t ws_size,
                              hipStream_t stream) {
  const float* x = (const float*)d_in[0];
  float* cent = (float*)d_out;                 // [B,K,C] fp32 state + output

  char* ws = (char*)d_ws;
  int* lists = (int*)ws;                                  // B*K*N ints (12,386,304 B)
  int* assign = lists + (size_t)BB * KK * NN;             // B*N ints   (589,824 B)
  int* counts = assign + (size_t)BB * NN;                 // B*K ints   (1,344 B)
  float* csq = (float*)(counts + BB * KK);                // B*K floats (1,344 B)
  int* idx_dec = (int*)(csq + BB * KK);                   // B*K ints   (1,344 B)

  decode_idx<<<1, 512, 0, stream>>>(d_in[1], idx_dec);
  gather_init<<<BB * KK, 256, 0, stream>>>(x, idx_dec, cent, csq);
  for (int it = 0; it < ITERS; ++it) {
    assign_np<<<BB * (NN / 256), 256, 0, stream>>>(x, cent, csq, assign);
    compact_np<<<BB * KK, 256, 0, stream>>>(assign, lists, counts);
    update_gather<<<BB * KK * 4, 64, 0, stream>>>(x, lists, counts, cent);
    csq_np<<<BB * KK, 256, 0, stream>>>(cent, csq);
  }
}

// Round 7
// 3266.212 us; speedup vs baseline: 1.1755x; 1.1755x over previous
//
#include <hip/hip_runtime.h>

// K-means, B=16, N=96*96=9216, C=256, K=21, 20 iterations.
//
// R8: PERF — fused update_full (compact->LDS + 128-deep gather + csq).
// NUMERICS FROZEN from R5/R6/R7 (PASS at absmax 4.882812e-04, deterministic).
//
// Correctness ledger: harness np reference is fp32; matching requires
// numpy-correlated fp32 rounding (R4 proved exact arithmetic lands the
// wrong basin). DO NOT change any float op, order, or precision:
//  - dots: ascending-c, 4 interleaved accs, separate mul/add roundings
//  - x_sq/csq: two 128-halves, 8 interleaved accs, pairwise combine
//  - d = (x_sq - 2*dot) + csq, first-min argmin
//  - centroid sums: GLOBAL ascending-n sequential fp32 chain per (k,c)
//    (batch width / uniform-guarded ascending tail do NOT reorder the chain
//     -- bit-verified in R6->R7)
//  - new_cent = cnt>0 ? sums/max(cnt,1) : old, fp32 state
//
// Perf evidence (R7 rocprof): update_gather 260us, occupancy 1.28% time-avg
// -> cluster-size SKEW: one dominant cluster's wave serializes cnt/16 round
// trips of ~2 dependent latencies (global lst load -> gather load). The add
// chain is inherently sequential, so feed it faster:
//  - list lives in LDS (no global-list RTT)
//  - 128 independent gather loads in flight per thread, one waitcnt, then
//    128 chained adds  => RTT amortized 8x deeper than R7
//  - compact + gather + csq in ONE kernel (fewer launches, hot assign in L2)
// No float atomics; output bit-identical every call (graph-safe).

#define BB 16
#define NN 9216
#define CC 256
#define KK 21
#define ITERS 20
#define QTR 2304     // NN/4: points per wave-quarter in compaction
#define BW 128       // gather batch width (loads in flight per thread)

// product with its own fp32 rounding, un-fusable into the consumer add
__device__ __forceinline__ float mul_sep(float a, float b) {
  float t = a * b;
  asm("" : "+v"(t));   // opaque pass-through: blocks FMA contraction
  return t;
}

// numpy pairwise_sum of v[i]*v[i], i in [0,128): 8 interleaved accumulators,
// combined ((r0+r1)+(r2+r3))+((r4+r5)+(r6+r7)). (n=256 splits into 2 halves.)
__device__ float np_half_sq(const float* v) {
  float r[8];
  #pragma unroll
  for (int j = 0; j < 8; ++j) r[j] = mul_sep(v[j], v[j]);
  for (int i = 8; i < 128; i += 8) {
    #pragma unroll
    for (int j = 0; j < 8; ++j) r[j] = __fadd_rn(r[j], mul_sep(v[i + j], v[i + j]));
  }
  return __fadd_rn(__fadd_rn(__fadd_rn(r[0], r[1]), __fadd_rn(r[2], r[3])),
                   __fadd_rn(__fadd_rn(r[4], r[5]), __fadd_rn(r[6], r[7])));
}

// ---------------------------------------------------------------- decode_idx
__global__ __launch_bounds__(512) void decode_idx(
    const void* __restrict__ raw, int* __restrict__ out) {
  __shared__ int all_ok;
  if (threadIdx.x == 0) all_ok = 1;
  __syncthreads();
  const long long* p64 = (const long long*)raw;
  const int* p32 = (const int*)raw;
  int t = threadIdx.x;
  long long v64 = 0;
  if (t < BB * KK) {
    v64 = p64[t];
    if (v64 < 0 || v64 >= NN) atomicAnd(&all_ok, 0);
  }
  __syncthreads();
  if (t < BB * KK) out[t] = all_ok ? (int)v64 : p32[t];
}

// ---------------------------------------------------------------- gather_init
// One block per (b,k): gather initial centroid; csq via numpy pairwise.
__global__ __launch_bounds__(256) void gather_init(
    const float* __restrict__ x, const int* __restrict__ idx_dec,
    float* __restrict__ cent, float* __restrict__ csq) {
  __shared__ float row[CC];
  int bk = blockIdx.x;
  int b = bk / KK;
  int c = threadIdx.x;
  int idx = idx_dec[bk];
  float v = x[((size_t)b * NN + idx) * CC + c];
  cent[(size_t)bk * CC + c] = v;
  row[c] = v;
  __syncthreads();
  if (threadIdx.x == 0)
    csq[bk] = __fadd_rn(np_half_sq(row), np_half_sq(row + 128));
}

// ---------------------------------------------------------------- assign_np
// (unchanged — numerics frozen)
__global__ __launch_bounds__(256) void assign_np(
    const float* __restrict__ x, const float* __restrict__ cent,
    const float* __restrict__ csq, int* __restrict__ assign) {
  const int nb = NN / 256;      // 36 blocks per batch
  int b = blockIdx.x / nb;
  int n = (blockIdx.x % nb) * 256 + threadIdx.x;
  const float* xp = x + ((size_t)b * NN + n) * CC;
  const float* cp = cent + (size_t)b * KK * CC;
  const float* cq = csq + b * KK;

  float q[KK][4];
  #pragma unroll
  for (int k = 0; k < KK; ++k)
    #pragma unroll
    for (int j = 0; j < 4; ++j) q[k][j] = 0.f;
  float rA[8], rB[8];
  #pragma unroll
  for (int j = 0; j < 8; ++j) { rA[j] = 0.f; rB[j] = 0.f; }

#define CHUNK16(C0, R)                                                        \
  do {                                                                        \
    float xv[16];                                                             \
    {                                                                         \
      float4 t0 = *(const float4*)(xp + (C0));                                \
      float4 t1 = *(const float4*)(xp + (C0) + 4);                            \
      float4 t2 = *(const float4*)(xp + (C0) + 8);                            \
      float4 t3 = *(const float4*)(xp + (C0) + 12);                           \
      xv[0] = t0.x; xv[1] = t0.y; xv[2] = t0.z; xv[3] = t0.w;                 \
      xv[4] = t1.x; xv[5] = t1.y; xv[6] = t1.z; xv[7] = t1.w;                 \
      xv[8] = t2.x; xv[9] = t2.y; xv[10] = t2.z; xv[11] = t2.w;               \
      xv[12] = t3.x; xv[13] = t3.y; xv[14] = t3.z; xv[15] = t3.w;             \
    }                                                                         \
    _Pragma("unroll")                                                         \
    for (int g = 0; g < 16; g += 8) {                                         \
      _Pragma("unroll")                                                       \
      for (int j = 0; j < 8; ++j)                                             \
        R[j] = __fadd_rn(R[j], mul_sep(xv[g + j], xv[g + j]));                \
    }                                                                         \
    _Pragma("unroll")                                                         \
    for (int k = 0; k < KK; ++k) {                                            \
      const float* cpk = cp + k * CC + (C0);  /* wave-uniform address */      \
      _Pragma("unroll")                                                       \
      for (int g2 = 0; g2 < 16; g2 += 4) {                                    \
        _Pragma("unroll")                                                     \
        for (int j = 0; j < 4; ++j)                                           \
          q[k][j] = __fadd_rn(q[k][j], mul_sep(xv[g2 + j], cpk[g2 + j]));     \
      }                                                                       \
    }                                                                         \
  } while (0)

  for (int c0 = 0; c0 < 128; c0 += 16) CHUNK16(c0, rA);
  for (int c0 = 128; c0 < 256; c0 += 16) CHUNK16(c0, rB);
#undef CHUNK16

  float hA = __fadd_rn(__fadd_rn(__fadd_rn(rA[0], rA[1]), __fadd_rn(rA[2], rA[3])),
                       __fadd_rn(__fadd_rn(rA[4], rA[5]), __fadd_rn(rA[6], rA[7])));
  float hB = __fadd_rn(__fadd_rn(__fadd_rn(rB[0], rB[1]), __fadd_rn(rB[2], rB[3])),
                       __fadd_rn(__fadd_rn(rB[4], rB[5]), __fadd_rn(rB[6], rB[7])));
  float xsq = __fadd_rn(hA, hB);

  float best = INFINITY;
  int bestk = 0;
  #pragma unroll
  for (int k = 0; k < KK; ++k) {
    float dk = __fadd_rn(__fadd_rn(q[k][0], q[k][2]), __fadd_rn(q[k][1], q[k][3]));
    float d = __fadd_rn(__fsub_rn(xsq, __fmul_rn(2.0f, dk)), cq[k]);
    if (d < best) { best = d; bestk = k; }   // first-min == np.argmin
  }
  assign[(size_t)b * NN + n] = bestk;
}

// ---------------------------------------------------------------- update_full
// One block per (b,k), 256 threads (thread = channel c, 4 waves).
// Phase A: two-pass ballot compaction of matched indices into ONE globally
//          ascending LDS list (pass 1 counts per quarter; pass 2 writes at
//          exact global positions). Same list content/order as R6/R7.
// Phase B: gather-sum in 128-deep register batches: 128 independent loads in
//          flight, one wait, then 128 strictly-sequential __fadd_rn (chain
//          order identical to R5's global ascending-n scan). Tail is
//          uniform-guarded ascending (bit-verified technique from R7).
// Phase C: new_cent = cnt>0 ? s/max(cnt,1) : old; csq via np_half_sq.
__global__ __launch_bounds__(256) void update_full(
    const float* __restrict__ x, const int* __restrict__ assign,
    float* __restrict__ cent, float* __restrict__ csq) {
  __shared__ int lst[NN];        // 36864 B (worst case: all points one cluster)
  __shared__ int wcnt_s[4];
  __shared__ float row[CC];
  int bk = blockIdx.x;
  int b = bk / KK, k = bk % KK;
  int lane = threadIdx.x & 63, w = threadIdx.x >> 6;
  const int* ap = assign + (size_t)b * NN + w * QTR;

  // pass 1: count matches in this wave's quarter (loads pipeline freely)
  int cnt = 0;
  for (int i = 0; i < QTR; i += 64) {
    unsigned long long m = __ballot(ap[i + lane] == k);
    cnt += (int)__popcll(m);
  }
  if (lane == 0) wcnt_s[w] = cnt;
  __syncthreads();
  int base = 0;
  for (int ww = 0; ww < 4; ++ww) if (ww < w) base += wcnt_s[ww];
  int total = wcnt_s[0] + wcnt_s[1] + wcnt_s[2] + wcnt_s[3];

  // pass 2: write matched indices at exact global ascending positions
  int pos = base;
  for (int i = 0; i < QTR; i += 64) {
    int a = ap[i + lane];
    unsigned long long m = __ballot(a == k);
    if (a == k)
      lst[pos + (int)__popcll(m & ((1ull << lane) - 1ull))] = w * QTR + i + lane;
    pos += (int)__popcll(m);
  }
  __syncthreads();

  // Phase B: gather-sum, batches of BW=128, chain strictly ascending
  int c = threadIdx.x;
  const float* xb = x + (size_t)b * NN * CC + c;
  float s = 0.f;
  int i = 0;
  for (; i + BW <= total; i += BW) {
    float v[BW];
    #pragma unroll
    for (int j = 0; j < BW; ++j) v[j] = xb[(size_t)lst[i + j] * CC];
    #pragma unroll
    for (int j = 0; j < BW; ++j) s = __fadd_rn(s, v[j]);   // chain in order
  }
  if (i < total) {
    int rem = total - i;                      // 1..BW-1, block-uniform
    float v[BW];
    #pragma unroll
    for (int j = 0; j < BW; ++j) {
      int idx = (j < rem) ? lst[i + j] : lst[i];
      v[j] = xb[(size_t)idx * CC];
    }
    #pragma unroll
    for (int j = 0; j < BW; ++j)
      if (j < rem) s = __fadd_rn(s, v[j]);    // uniform guard, ascending
  }

  // Phase C: update + csq
  float old = cent[(size_t)bk * CC + c];
  float dv = s / fmaxf((float)total, 1.0f);   // fp32 IEEE division (as R5)
  float nc = (total > 0) ? dv : old;
  cent[(size_t)bk * CC + c] = nc;
  row[c] = nc;
  __syncthreads();
  if (threadIdx.x == 0)
    csq[bk] = __fadd_rn(np_half_sq(row), np_half_sq(row + 128));
}

// ---------------------------------------------------------------- launch
extern "C" void kernel_launch(void* const* d_in, const int* in_sizes, int n_in,
                              void* d_out, int out_size, void* d_ws, size_t ws_size,
                              hipStream_t stream) {
  const float* x = (const float*)d_in[0];
  float* cent = (float*)d_out;                 // [B,K,C] fp32 state + output

  char* ws = (char*)d_ws;
  int* assign = (int*)ws;                           // B*N ints   (589,824 B)
  float* csq = (float*)(ws + (size_t)BB * NN * 4);  // B*K floats (1,344 B)
  int* idx_dec = (int*)(csq + BB * KK);             // B*K ints   (1,344 B)

  decode_idx<<<1, 512, 0, stream>>>(d_in[1], idx_dec);
  gather_init<<<BB * KK, 256, 0, stream>>>(x, idx_dec, cent, csq);
  for (int it = 0; it < ITERS; ++it) {
    assign_np<<<BB * (NN / 256), 256, 0, stream>>>(x, cent, csq, assign);
    update_full<<<BB * KK, 256, 0, stream>>>(x, assign, cent, csq);
  }
}